// Round 12
// baseline (13665.688 us; speedup 1.0000x reference)
//
#include <hip/hip_runtime.h>

typedef _Float16 f16;
typedef _Float16 f16x8 __attribute__((ext_vector_type(8)));
typedef float f32x16 __attribute__((ext_vector_type(16)));

#define HID   512
#define NSTEP 100
#define WMAT  786432      // halfs per packed weight matrix (1536*512)

__device__ __forceinline__ float sigmoid_f(float x) {
  return 1.0f / (1.0f + __expf(-x));
}
__device__ __forceinline__ float tanh_f(float x) {
  float e = __expf(2.0f * x);
  return 1.0f - 2.0f / (e + 1.0f);
}
__device__ __forceinline__ f32x16 mfma16(f16x8 a, f16x8 b, f32x16 c) {
  return __builtin_amdgcn_mfma_f32_32x32x16_f16(a, b, c, 0, 0, 0);
}
__device__ __forceinline__ f32x16 zero16() {
  f32x16 z;
#pragma unroll
  for (int i = 0; i < 16; ++i) z[i] = 0.f;
  return z;
}

// ---- weight pack: fp32 [1536][512] row-major -> B-fragment-packed fp16 ----
__global__ void pack_weights(const float* __restrict__ W, f16* __restrict__ out) {
  int t = blockIdx.x * 256 + threadIdx.x;
  if (t >= 48 * 32 * 64) return;
  int lane = t & 63;
  int kt   = (t >> 6) & 31;
  int ct   = t >> 11;
  int gate = ct * 32 + (lane & 31);
  int k0   = kt * 16 + (lane >> 5) * 8;
  const float* src = W + gate * HID + k0;
  f16x8 v;
#pragma unroll
  for (int i = 0; i < 8; ++i) v[i] = (f16)src[i];
  *(f16x8*)(out + (size_t)t * 8) = v;
}

// w_ih1 + bias -> K=16 B tiles: slots [w0,w1,w2, bias, 0...]
__global__ void pack_wx(const float* __restrict__ W, const float* __restrict__ bi,
                        const float* __restrict__ bh, f16* __restrict__ out) {
  int t = blockIdx.x * 256 + threadIdx.x;
  if (t >= 48 * 64) return;
  int lane = t & 63;
  int ct   = t >> 6;
  int col  = ct * 32 + (lane & 31);
  int k0   = (lane >> 5) * 8;
  f16x8 v;
#pragma unroll
  for (int i = 0; i < 8; ++i) {
    int k = k0 + i;
    float x = 0.f;
    if (k < 3)       x = W[col * 3 + k];
    else if (k == 3) x = (ct < 32) ? (bi[col] + bh[col]) : bi[col];
    v[i] = (f16)x;
  }
  *(f16x8*)(out + (size_t)t * 8) = v;
}

// combined biases: [0..1023]=bi+bh (r,z), [1024..1535]=bi_n, [1536..2047]=bh_n
__global__ void pack_bias(const float* __restrict__ bi, const float* __restrict__ bh,
                          float* __restrict__ out) {
  int j = blockIdx.x * 256 + threadIdx.x;
  if (j < 1024)      out[j] = bi[j] + bh[j];
  else if (j < 1536) out[j] = bi[j];
  else if (j < 2048) out[j] = bh[j - 512];
}

// ---- per-pass macros; REV reverses the kt sweep direction (serpentine) ----
// L2 working-set fix: the step sweeps 4.5 MB of weights through a 4 MB/XCD L2.
// Alternating pass order + kt direction each step cuts re-reference distance
// below capacity for ~half the tiles -> L2 hits instead of L3 misses.

#define P_L1R(REV)                                                              \
  {                                                                             \
    f16x8 ax0 = *(const f16x8*)((const char*)xs16 + xoff0);                     \
    f16x8 ax1 = *(const f16x8*)((const char*)xs16 + xoff1);                     \
    f32x16 zz = zero16();                                                       \
    _Pragma("unroll")                                                           \
    for (int c = 0; c < 2; ++c) {                                               \
      f16x8 bx = *(const f16x8*)(Wx + (size_t)(ct0 + c) * 512 + lane * 8);      \
      aR[c][0] = mfma16(ax0, bx, zz);                                           \
      aR[c][1] = mfma16(ax1, bx, zz);                                           \
    }                                                                           \
    const f16* B0 = Wp + (size_t)ct0 * 16384 + lane * 8;                        \
    const f16* B1 = Wp + (size_t)ct1 * 16384 + lane * 8;                        \
    _Pragma("unroll 2")                                                         \
    for (int k2 = 0; k2 < 32; ++k2) {                                           \
      const int kt = (REV) ? 31 - k2 : k2;                                      \
      const int koff = ((kt << 5) | klo) ^ patA;                                \
      f16x8 a0 = *(const f16x8*)((const char*)h1s + rbase + koff);              \
      f16x8 a1 = *(const f16x8*)((const char*)h1s + 32768 + rbase + koff);      \
      f16x8 b0 = *(const f16x8*)(B0 + kt * 512);                                \
      f16x8 b1 = *(const f16x8*)(B1 + kt * 512);                                \
      aR[0][0] = mfma16(a0, b0, aR[0][0]);  aR[0][1] = mfma16(a1, b0, aR[0][1]);\
      aR[1][0] = mfma16(a0, b1, aR[1][0]);  aR[1][1] = mfma16(a1, b1, aR[1][1]);\
    }                                                                           \
  }

#define P_L1NH(REV)                                                             \
  {                                                                             \
    f32x16 zz = zero16();                                                       \
    aH[0][0] = zz; aH[0][1] = zz; aH[1][0] = zz; aH[1][1] = zz;                 \
    const f16* B0 = Wp + (size_t)(32 + ct0) * 16384 + lane * 8;                 \
    const f16* B1 = Wp + (size_t)(32 + ct1) * 16384 + lane * 8;                 \
    _Pragma("unroll 2")                                                         \
    for (int k2 = 0; k2 < 32; ++k2) {                                           \
      const int kt = (REV) ? 31 - k2 : k2;                                      \
      const int koff = ((kt << 5) | klo) ^ patA;                                \
      f16x8 a0 = *(const f16x8*)((const char*)h1s + rbase + koff);              \
      f16x8 a1 = *(const f16x8*)((const char*)h1s + 32768 + rbase + koff);      \
      f16x8 b0 = *(const f16x8*)(B0 + kt * 512);                                \
      f16x8 b1 = *(const f16x8*)(B1 + kt * 512);                                \
      aH[0][0] = mfma16(a0, b0, aH[0][0]);  aH[0][1] = mfma16(a1, b0, aH[0][1]);\
      aH[1][0] = mfma16(a0, b1, aH[1][0]);  aH[1][1] = mfma16(a1, b1, aH[1][1]);\
    }                                                                           \
  }

#define C1_COMBINE                                                              \
  {                                                                             \
    _Pragma("unroll")                                                           \
    for (int c = 0; c < 2; ++c) {                                               \
      const float bnh = bsh[jw + (c << 5) + colid];                             \
      _Pragma("unroll")                                                         \
      for (int tl = 0; tl < 2; ++tl)                                            \
        _Pragma("unroll")                                                       \
        for (int q = 0; q < 16; ++q)                                            \
          aH[c][tl][q] = sigmoid_f(aR[c][tl][q]) * (aH[c][tl][q] + bnh);        \
    }                                                                           \
    f16x8 ax0 = *(const f16x8*)((const char*)xs16 + xoff0);                     \
    f16x8 ax1 = *(const f16x8*)((const char*)xs16 + xoff1);                     \
    _Pragma("unroll")                                                           \
    for (int c = 0; c < 2; ++c) {                                               \
      f16x8 bx = *(const f16x8*)(Wx + (size_t)(32 + ct0 + c) * 512 + lane * 8); \
      aH[c][0] = mfma16(ax0, bx, aH[c][0]);                                     \
      aH[c][1] = mfma16(ax1, bx, aH[c][1]);                                     \
    }                                                                           \
  }

#define P_L1Z(REV)                                                              \
  {                                                                             \
    f16x8 ax0 = *(const f16x8*)((const char*)xs16 + xoff0);                     \
    f16x8 ax1 = *(const f16x8*)((const char*)xs16 + xoff1);                     \
    f32x16 zz = zero16();                                                       \
    _Pragma("unroll")                                                           \
    for (int c = 0; c < 2; ++c) {                                               \
      f16x8 bx = *(const f16x8*)(Wx + (size_t)(16 + ct0 + c) * 512 + lane * 8); \
      aZ[c][0] = mfma16(ax0, bx, zz);                                           \
      aZ[c][1] = mfma16(ax1, bx, zz);                                           \
    }                                                                           \
    const f16* B0 = Wp + (size_t)(16 + ct0) * 16384 + lane * 8;                 \
    const f16* B1 = Wp + (size_t)(16 + ct1) * 16384 + lane * 8;                 \
    _Pragma("unroll 2")                                                         \
    for (int k2 = 0; k2 < 32; ++k2) {                                           \
      const int kt = (REV) ? 31 - k2 : k2;                                      \
      const int koff = ((kt << 5) | klo) ^ patA;                                \
      f16x8 a0 = *(const f16x8*)((const char*)h1s + rbase + koff);              \
      f16x8 a1 = *(const f16x8*)((const char*)h1s + 32768 + rbase + koff);      \
      f16x8 b0 = *(const f16x8*)(B0 + kt * 512);                                \
      f16x8 b1 = *(const f16x8*)(B1 + kt * 512);                                \
      aZ[0][0] = mfma16(a0, b0, aZ[0][0]);  aZ[0][1] = mfma16(a1, b0, aZ[0][1]);\
      aZ[1][0] = mfma16(a0, b1, aZ[1][0]);  aZ[1][1] = mfma16(a1, b1, aZ[1][1]);\
    }                                                                           \
  }

#define P_L2R(REV)                                                              \
  {                                                                             \
    f32x16 zz = zero16();                                                       \
    aR[0][0] = zz; aR[0][1] = zz; aR[1][0] = zz; aR[1][1] = zz;                 \
    const f16* Bi0 = Wi2 + (size_t)ct0 * 16384 + lane * 8;                      \
    const f16* Bi1 = Wi2 + (size_t)ct1 * 16384 + lane * 8;                      \
    const f16* Bh0 = Wh2 + (size_t)ct0 * 16384 + lane * 8;                      \
    const f16* Bh1 = Wh2 + (size_t)ct1 * 16384 + lane * 8;                      \
    _Pragma("unroll 2")                                                         \
    for (int k2 = 0; k2 < 32; ++k2) {                                           \
      const int kt = (REV) ? 31 - k2 : k2;                                      \
      const int koff = ((kt << 5) | klo) ^ patA;                                \
      f16x8 x0 = *(const f16x8*)((const char*)h1s + rbase + koff);              \
      f16x8 x1 = *(const f16x8*)((const char*)h1s + 32768 + rbase + koff);      \
      f16x8 y0 = *(const f16x8*)((const char*)h2s + rbase + koff);              \
      f16x8 y1 = *(const f16x8*)((const char*)h2s + 32768 + rbase + koff);      \
      f16x8 bi0 = *(const f16x8*)(Bi0 + kt * 512);                              \
      f16x8 bi1 = *(const f16x8*)(Bi1 + kt * 512);                              \
      f16x8 bh0 = *(const f16x8*)(Bh0 + kt * 512);                              \
      f16x8 bh1 = *(const f16x8*)(Bh1 + kt * 512);                              \
      aR[0][0] = mfma16(x0, bi0, aR[0][0]);  aR[0][0] = mfma16(y0, bh0, aR[0][0]);\
      aR[0][1] = mfma16(x1, bi0, aR[0][1]);  aR[0][1] = mfma16(y1, bh0, aR[0][1]);\
      aR[1][0] = mfma16(x0, bi1, aR[1][0]);  aR[1][0] = mfma16(y0, bh1, aR[1][0]);\
      aR[1][1] = mfma16(x1, bi1, aR[1][1]);  aR[1][1] = mfma16(y1, bh1, aR[1][1]);\
    }                                                                           \
  }

#define P_L2NH(REV)                                                             \
  {                                                                             \
    f32x16 zz = zero16();                                                       \
    aH[0][0] = zz; aH[0][1] = zz; aH[1][0] = zz; aH[1][1] = zz;                 \
    const f16* B0 = Wh2 + (size_t)(32 + ct0) * 16384 + lane * 8;                \
    const f16* B1 = Wh2 + (size_t)(32 + ct1) * 16384 + lane * 8;                \
    _Pragma("unroll 2")                                                         \
    for (int k2 = 0; k2 < 32; ++k2) {                                           \
      const int kt = (REV) ? 31 - k2 : k2;                                      \
      const int koff = ((kt << 5) | klo) ^ patA;                                \
      f16x8 y0 = *(const f16x8*)((const char*)h2s + rbase + koff);              \
      f16x8 y1 = *(const f16x8*)((const char*)h2s + 32768 + rbase + koff);      \
      f16x8 b0 = *(const f16x8*)(B0 + kt * 512);                                \
      f16x8 b1 = *(const f16x8*)(B1 + kt * 512);                                \
      aH[0][0] = mfma16(y0, b0, aH[0][0]);  aH[0][1] = mfma16(y1, b0, aH[0][1]);\
      aH[1][0] = mfma16(y0, b1, aH[1][0]);  aH[1][1] = mfma16(y1, b1, aH[1][1]);\
    }                                                                           \
  }

#define C2_COMBINE                                                              \
  {                                                                             \
    _Pragma("unroll")                                                           \
    for (int c = 0; c < 2; ++c) {                                               \
      const int j = jw + (c << 5) + colid;                                      \
      const float br  = bsh[512 + j];                                           \
      const float bnh = bsh[2048 + j];                                          \
      _Pragma("unroll")                                                         \
      for (int tl = 0; tl < 2; ++tl)                                            \
        _Pragma("unroll")                                                       \
        for (int q = 0; q < 16; ++q)                                            \
          aH[c][tl][q] = sigmoid_f(aR[c][tl][q] + br) * (aH[c][tl][q] + bnh);   \
    }                                                                           \
  }

#define P_L2Z(REV)                                                              \
  {                                                                             \
    f32x16 zz = zero16();                                                       \
    aZ[0][0] = zz; aZ[0][1] = zz; aZ[1][0] = zz; aZ[1][1] = zz;                 \
    const f16* Bi0 = Wi2 + (size_t)(16 + ct0) * 16384 + lane * 8;               \
    const f16* Bi1 = Wi2 + (size_t)(16 + ct1) * 16384 + lane * 8;               \
    const f16* Bh0 = Wh2 + (size_t)(16 + ct0) * 16384 + lane * 8;               \
    const f16* Bh1 = Wh2 + (size_t)(16 + ct1) * 16384 + lane * 8;               \
    _Pragma("unroll 2")                                                         \
    for (int k2 = 0; k2 < 32; ++k2) {                                           \
      const int kt = (REV) ? 31 - k2 : k2;                                      \
      const int koff = ((kt << 5) | klo) ^ patA;                                \
      f16x8 x0 = *(const f16x8*)((const char*)h1s + rbase + koff);              \
      f16x8 x1 = *(const f16x8*)((const char*)h1s + 32768 + rbase + koff);      \
      f16x8 y0 = *(const f16x8*)((const char*)h2s + rbase + koff);              \
      f16x8 y1 = *(const f16x8*)((const char*)h2s + 32768 + rbase + koff);      \
      f16x8 bi0 = *(const f16x8*)(Bi0 + kt * 512);                              \
      f16x8 bi1 = *(const f16x8*)(Bi1 + kt * 512);                              \
      f16x8 bh0 = *(const f16x8*)(Bh0 + kt * 512);                              \
      f16x8 bh1 = *(const f16x8*)(Bh1 + kt * 512);                              \
      aZ[0][0] = mfma16(x0, bi0, aZ[0][0]);  aZ[0][0] = mfma16(y0, bh0, aZ[0][0]);\
      aZ[0][1] = mfma16(x1, bi0, aZ[0][1]);  aZ[0][1] = mfma16(y1, bh0, aZ[0][1]);\
      aZ[1][0] = mfma16(x0, bi1, aZ[1][0]);  aZ[1][0] = mfma16(y0, bh1, aZ[1][0]);\
      aZ[1][1] = mfma16(x1, bi1, aZ[1][1]);  aZ[1][1] = mfma16(y1, bh1, aZ[1][1]);\
    }                                                                           \
  }

#define P_L2NI(REV)                                                             \
  {                                                                             \
    const f16* B0 = Wi2 + (size_t)(32 + ct0) * 16384 + lane * 8;                \
    const f16* B1 = Wi2 + (size_t)(32 + ct1) * 16384 + lane * 8;                \
    _Pragma("unroll 2")                                                         \
    for (int k2 = 0; k2 < 32; ++k2) {                                           \
      const int kt = (REV) ? 31 - k2 : k2;                                      \
      const int koff = ((kt << 5) | klo) ^ patA;                                \
      f16x8 x0 = *(const f16x8*)((const char*)h1s + rbase + koff);              \
      f16x8 x1 = *(const f16x8*)((const char*)h1s + 32768 + rbase + koff);      \
      f16x8 b0 = *(const f16x8*)(B0 + kt * 512);                                \
      f16x8 b1 = *(const f16x8*)(B1 + kt * 512);                                \
      aH[0][0] = mfma16(x0, b0, aH[0][0]);  aH[0][1] = mfma16(x1, b0, aH[0][1]);\
      aH[1][0] = mfma16(x0, b1, aH[1][0]);  aH[1][1] = mfma16(x1, b1, aH[1][1]);\
    }                                                                           \
  }

__global__ __launch_bounds__(512, 2) void gru_fused(
    const float* __restrict__ z,
    const float* __restrict__ fc_w,    // [3][512]  fp32
    const float* __restrict__ fc_b,    // [3]
    const f16*  __restrict__ Wp,       // packed Whh1 | Wih2 | Whh2
    const f16*  __restrict__ Wx,       // packed w_ih1 K-ext tiles (bias in slot 3)
    const float* __restrict__ Bb,      // bias1[2048] | bias2[2048]
    float* __restrict__ out)           // [B][100][3] fp32
{
  __shared__ f16   h1s[64 * HID];       // 64 KB  [tile(2)][row(32)][col(512)]
  __shared__ f16   h2s[64 * HID];       // 64 KB
  __shared__ f16   xs16[64 * 16];       // 2 KB   K-ext A-tile: [x0,x1,x2,1,0..]
  __shared__ float fcwT[3 * HID];       // 6 KB   pos(k) = (k&7)*64 + (k>>3)
  __shared__ float xsf[64 * 4];         // 1 KB   fp32 x state
  __shared__ float bsh[5 * 512];        // 10 KB  [b1nh | b2r | b2z | b2ni | b2nh]

  const int tid  = threadIdx.x;
  const int lane = tid & 63;
  const int wv   = tid >> 6;            // 0..7
  const int b0   = blockIdx.x * 64;

  {
    f16x8 z8 = {0, 0, 0, 0, 0, 0, 0, 0};
    for (int i = tid; i < 64 * HID / 8; i += 512) {
      ((f16x8*)h1s)[i] = z8;
      ((f16x8*)h2s)[i] = z8;
    }
    if (tid < 64) {
#pragma unroll
      for (int k = 0; k < 16; ++k) xs16[tid * 16 + k] = (f16)((k == 3) ? 1.f : 0.f);
    }
    if (tid < HID) {
      const int pos = ((tid & 7) << 6) + (tid >> 3);
      fcwT[pos]        = fc_w[tid];
      fcwT[512 + pos]  = fc_w[512 + tid];
      fcwT[1024 + pos] = fc_w[1024 + tid];
      bsh[tid]         = Bb[1536 + tid];          // b1nh
      bsh[512 + tid]   = Bb[2048 + tid];          // b2r
      bsh[1024 + tid]  = Bb[2048 + 512 + tid];    // b2z
      bsh[1536 + tid]  = Bb[2048 + 1024 + tid];   // b2ni
      bsh[2048 + tid]  = Bb[2048 + 1536 + tid];   // b2nh
    }
  }
  __syncthreads();
  if (tid < 64 * 3) {
    const int rr = tid / 3, oo = tid - rr * 3;
    float v = z[(size_t)(b0 + rr) * 6 + 3 + oo];
    xsf[rr * 4 + oo] = v;
    xs16[rr * 16 + oo] = (f16)v;
    out[(size_t)(b0 + rr) * 300 + oo] = v;     // t = 0 output
  }
  __syncthreads();

  const int colid = lane & 31;
  const int khalf = lane >> 5;
  const int klo   = khalf << 4;
  const int patA  = (colid & 7) << 4;
  const int rbase = colid * 1024;
  const int jw    = wv << 6;            // wave owns cols [jw, jw+64)
  const int ct0   = wv << 1;
  const int ct1   = ct0 + 1;

  const f16* Wi2 = Wp + WMAT;
  const f16* Wh2 = Wp + 2 * WMAT;

  const float fb0 = fc_b[0], fb1 = fc_b[1], fb2 = fc_b[2];
  const int xoff0 = colid * 32 + klo;
  const int xoff1 = (32 + colid) * 32 + klo;

  for (int t = 1; t < NSTEP; ++t) {
    f32x16 aR[2][2], aH[2][2], aZ[2][2];   // acc-class parks only

    // ===== L1 passes (serpentine: order + kt direction flip with t parity) =====
    if (!(t & 1)) {
      P_L1R(0)  P_L1NH(0)  C1_COMBINE  P_L1Z(0)
    } else {
      P_L1NH(1) P_L1R(1)   C1_COMBINE  P_L1Z(1)
    }
    __syncthreads();   // all h1_old reads done
    // ---- epi1 (in place): h1 = (1-sigma(aZ))*tanh(aH) + sigma(aZ)*h1_old ----
#pragma unroll
    for (int c = 0; c < 2; ++c) {
      const int jxc = 2 * (jw + (c << 5) + colid);
#pragma unroll
      for (int tl = 0; tl < 2; ++tl)
#pragma unroll
        for (int q = 0; q < 16; ++q) {
          const int row = (q & 3) + ((q >> 2) << 3) + (khalf << 2);
          f16* hp = (f16*)((char*)h1s + tl * 32768 + row * 1024 + (jxc ^ ((row & 7) << 4)));
          float zt = sigmoid_f(aZ[c][tl][q]);
          float n  = tanh_f(aH[c][tl][q]);
          float hold = (float)*hp;
          *hp = (f16)((1.0f - zt) * n + zt * hold);
        }
    }
    __syncthreads();   // h1_new visible

    // ===== L2 passes (serpentine) =====
    if (!(t & 1)) {
      P_L2R(0)  P_L2NH(0)  C2_COMBINE  P_L2Z(0)  P_L2NI(0)
    } else {
      P_L2NH(1) P_L2R(1)   C2_COMBINE  P_L2Z(1)  P_L2NI(1)
    }
    __syncthreads();   // all h2_old reads done
    // ---- epi2 (in place): h2 = (1-sigma(aZ+b2z))*tanh(aH+b2ni) + sigma(...)*h2_old ----
#pragma unroll
    for (int c = 0; c < 2; ++c) {
      const int j = jw + (c << 5) + colid;
      const float bz  = bsh[1024 + j];
      const float bni = bsh[1536 + j];
      const int jxc = 2 * j;
#pragma unroll
      for (int tl = 0; tl < 2; ++tl)
#pragma unroll
        for (int q = 0; q < 16; ++q) {
          const int row = (q & 3) + ((q >> 2) << 3) + (khalf << 2);
          f16* hp = (f16*)((char*)h2s + tl * 32768 + row * 1024 + (jxc ^ ((row & 7) << 4)));
          float zt = sigmoid_f(aZ[c][tl][q] + bz);
          float n  = tanh_f(aH[c][tl][q] + bni);
          float hold = (float)*hp;
          *hp = (f16)((1.0f - zt) * n + zt * hold);
        }
    }
    __syncthreads();   // h2_new visible

    // ================= FC head: 8 waves x 8 rows, 8-lane shuffle reduce =================
    {
      const int rowg = (wv << 3) + (lane >> 3);   // global row 0..63
      const int tl   = rowg >> 5;
      const int rit  = rowg & 31;
      const int sl   = lane & 7;                  // k-slice of 64
      const char* hb = (const char*)h2s + tl * 32768 + rit * 1024;
      const int pat = (rit & 7) << 4;
      float p0 = 0.f, p1 = 0.f, p2 = 0.f;
#pragma unroll
      for (int j = 0; j < 8; ++j) {
        f16x8 hh = *(const f16x8*)(hb + (((sl << 7) | (j << 4)) ^ pat));
#pragma unroll
        for (int i = 0; i < 8; ++i) {
          const float hf = (float)hh[i];
          const int pos = (i << 6) + (sl << 3) + j;
          p0 = fmaf(hf, fcwT[pos], p0);
          p1 = fmaf(hf, fcwT[512 + pos], p1);
          p2 = fmaf(hf, fcwT[1024 + pos], p2);
        }
      }
#pragma unroll
      for (int m = 1; m < 8; m <<= 1) {
        p0 += __shfl_xor(p0, m, 64);
        p1 += __shfl_xor(p1, m, 64);
        p2 += __shfl_xor(p2, m, 64);
      }
      if (sl == 0) {
        float x0 = xsf[(rowg << 2) + 0] + 0.1f * tanh_f(p0 + fb0);
        float x1 = xsf[(rowg << 2) + 1] + 0.1f * tanh_f(p1 + fb1);
        float x2 = xsf[(rowg << 2) + 2] + 0.1f * tanh_f(p2 + fb2);
        xsf[(rowg << 2) + 0] = x0;  xs16[rowg * 16 + 0] = (f16)x0;
        xsf[(rowg << 2) + 1] = x1;  xs16[rowg * 16 + 1] = (f16)x1;
        xsf[(rowg << 2) + 2] = x2;  xs16[rowg * 16 + 2] = (f16)x2;
        float* op = out + (size_t)(b0 + rowg) * 300 + (size_t)t * 3;
        op[0] = x0; op[1] = x1; op[2] = x2;
      }
    }
    __syncthreads();
  }
}

extern "C" void kernel_launch(void* const* d_in, const int* in_sizes, int n_in,
                              void* d_out, int out_size, void* d_ws, size_t ws_size,
                              hipStream_t stream) {
  const float* z     = (const float*)d_in[0];
  const float* w_ih1 = (const float*)d_in[1];
  const float* w_hh1 = (const float*)d_in[2];
  const float* b_ih1 = (const float*)d_in[3];
  const float* b_hh1 = (const float*)d_in[4];
  const float* w_ih2 = (const float*)d_in[5];
  const float* w_hh2 = (const float*)d_in[6];
  const float* b_ih2 = (const float*)d_in[7];
  const float* b_hh2 = (const float*)d_in[8];
  const float* fc_w  = (const float*)d_in[9];
  const float* fc_b  = (const float*)d_in[10];
  float* out = (float*)d_out;

  f16*   Wp = (f16*)d_ws;                                          // 3 * 1.5 MB packed fp16
  f16*   Wx = (f16*)((char*)d_ws + (size_t)3 * WMAT * 2);          // 48 KB packed w_ih1+bias
  float* Bb = (float*)((char*)d_ws + (size_t)3 * WMAT * 2 + 48 * 512 * 2);

  const int nbatch = in_sizes[0] / 6;

  pack_weights<<<384, 256, 0, stream>>>(w_hh1, Wp);
  pack_weights<<<384, 256, 0, stream>>>(w_ih2, Wp + WMAT);
  pack_weights<<<384, 256, 0, stream>>>(w_hh2, Wp + 2 * WMAT);
  pack_wx<<<12, 256, 0, stream>>>(w_ih1, b_ih1, b_hh1, Wx);
  pack_bias<<<8, 256, 0, stream>>>(b_ih1, b_hh1, Bb);
  pack_bias<<<8, 256, 0, stream>>>(b_ih2, b_hh2, Bb + 2048);

  gru_fused<<<nbatch / 64, 512, 0, stream>>>(z, fc_w, fc_b, Wp, Wx, Bb, out);
}

// Round 13
// 11305.403 us; speedup vs baseline: 1.2088x; 1.2088x over previous
//
#include <hip/hip_runtime.h>

typedef _Float16 f16;
typedef _Float16 f16x8 __attribute__((ext_vector_type(8)));
typedef float f32x16 __attribute__((ext_vector_type(16)));
typedef unsigned int u32;
typedef u32 u32x2v __attribute__((ext_vector_type(2)));

#define HID   512
#define NSTEP 100

// e5m2 byte -> f16 is exact: f16 bits = byte << 8. Decode 8 bytes -> f16x8.
__device__ __forceinline__ f16x8 dec8(u32x2v w) {
  union { u32 u[4]; f16x8 v; } r;
  const u32 a = w[0], b = w[1];
  r.u[0] = ((a & 0x000000ffu) << 8) | ((a & 0x0000ff00u) << 16);
  r.u[1] = ((a >> 8) & 0x0000ff00u) | (a & 0xff000000u);
  r.u[2] = ((b & 0x000000ffu) << 8) | ((b & 0x0000ff00u) << 16);
  r.u[3] = ((b >> 8) & 0x0000ff00u) | (b & 0xff000000u);
  return r.v;
}

__device__ __forceinline__ float sigmoid_f(float x) {
  return 1.0f / (1.0f + __expf(-x));
}
__device__ __forceinline__ float tanh_f(float x) {
  float e = __expf(2.0f * x);
  return 1.0f - 2.0f / (e + 1.0f);
}
__device__ __forceinline__ f32x16 mfma16(f16x8 a, f16x8 b, f32x16 c) {
  return __builtin_amdgcn_mfma_f32_32x32x16_f16(a, b, c, 0, 0, 0);
}
__device__ __forceinline__ f32x16 zero16() {
  f32x16 z;
#pragma unroll
  for (int i = 0; i < 16; ++i) z[i] = 0.f;
  return z;
}

// ---- n-gate pack (f16): rows 1024..1535 -> [ct(16)][kt(32)][lane(64)][i(8)] ----
__global__ void pack_wn(const float* __restrict__ W, f16* __restrict__ out) {
  int t = blockIdx.x * 256 + threadIdx.x;
  if (t >= 16 * 32 * 64) return;
  int lane = t & 63;
  int kt   = (t >> 6) & 31;
  int ct   = t >> 11;
  int gate = 1024 + ct * 32 + (lane & 31);
  int k0   = kt * 16 + (lane >> 5) * 8;
  const float* src = W + gate * HID + k0;
  f16x8 v;
#pragma unroll
  for (int i = 0; i < 8; ++i) v[i] = (f16)src[i];
  *(f16x8*)(out + (size_t)t * 8) = v;
}

// ---- r,z gate pack (bf8 e5m2, RNE): rows 0..1023 -> [g(2)][ct(16)][kt(32)][lane][i] bytes ----
__global__ void pack_w8(const float* __restrict__ W, unsigned char* __restrict__ out) {
  int t = blockIdx.x * 256 + threadIdx.x;
  if (t >= 2 * 16 * 32 * 64) return;
  int lane = t & 63;
  int kt   = (t >> 6) & 31;
  int ct   = (t >> 11) & 15;
  int g    = t >> 15;
  int gate = g * 512 + ct * 32 + (lane & 31);
  int k0   = kt * 16 + (lane >> 5) * 8;
  const float* src = W + gate * HID + k0;
  unsigned char v[8];
#pragma unroll
  for (int i = 0; i < 8; ++i) {
    f16 h = (f16)src[i];
    unsigned short hb;
    __builtin_memcpy(&hb, &h, 2);
    v[i] = (unsigned char)((hb + 0x80u) >> 8);   // e5m2 = f16 top byte, RNE-ish
  }
  unsigned char* dst = out + (size_t)t * 8;
#pragma unroll
  for (int i = 0; i < 8; ++i) dst[i] = v[i];
}

// w_ih1 + bias -> K=16 B tiles: slots [w0,w1,w2, bias, 0...]
__global__ void pack_wx(const float* __restrict__ W, const float* __restrict__ bi,
                        const float* __restrict__ bh, f16* __restrict__ out) {
  int t = blockIdx.x * 256 + threadIdx.x;
  if (t >= 48 * 64) return;
  int lane = t & 63;
  int ct   = t >> 6;
  int col  = ct * 32 + (lane & 31);
  int k0   = (lane >> 5) * 8;
  f16x8 v;
#pragma unroll
  for (int i = 0; i < 8; ++i) {
    int k = k0 + i;
    float x = 0.f;
    if (k < 3)       x = W[col * 3 + k];
    else if (k == 3) x = (ct < 32) ? (bi[col] + bh[col]) : bi[col];
    v[i] = (f16)x;
  }
  *(f16x8*)(out + (size_t)t * 8) = v;
}

// combined biases: [0..1023]=bi+bh (r,z), [1024..1535]=bi_n, [1536..2047]=bh_n
__global__ void pack_bias(const float* __restrict__ bi, const float* __restrict__ bh,
                          float* __restrict__ out) {
  int j = blockIdx.x * 256 + threadIdx.x;
  if (j < 1024)      out[j] = bi[j] + bh[j];
  else if (j < 1536) out[j] = bi[j];
  else if (j < 2048) out[j] = bh[j - 512];
}

// Persistent per-block GRU, BT=64, 8 waves x 64 cols, grid=256, ONE generation.
// R11's acc-parking structure (spill-free) + L2-RESIDENT WEIGHTS: r,z gate
// weights stored bf8-e5m2 (decode = byte<<8 to f16 in-register), n gates f16.
// Working set 3.05 MB < 4 MB/XCD L2 -> weight reads become L2 hits after step 1.
__global__ __launch_bounds__(512, 2) void gru_fused(
    const float* __restrict__ z,
    const float* __restrict__ fc_w,    // [3][512]  fp32
    const float* __restrict__ fc_b,    // [3]
    const f16*  __restrict__ Wn,       // f16 n-gate tiles [m(3)][ct(16)][kt(32)][lane][8]
    const unsigned char* __restrict__ W8,  // bf8 r,z tiles [m(3)][g(2)][ct(16)][kt(32)][lane][8]
    const f16*  __restrict__ Wx,       // packed w_ih1 K-ext tiles (bias in slot 3)
    const float* __restrict__ Bb,      // bias1[2048] | bias2[2048]
    float* __restrict__ out)           // [B][100][3] fp32
{
  __shared__ f16   h1s[64 * HID];       // 64 KB  [tile(2)][row(32)][col(512)]
  __shared__ f16   h2s[64 * HID];       // 64 KB
  __shared__ f16   xs16[64 * 16];       // 2 KB   K-ext A-tile: [x0,x1,x2,1,0..]
  __shared__ float fcwT[3 * HID];       // 6 KB   pos(k) = (k&7)*64 + (k>>3)
  __shared__ float xsf[64 * 4];         // 1 KB   fp32 x state
  __shared__ float bsh[5 * 512];        // 10 KB  [b1nh | b2r | b2z | b2ni | b2nh]

  const int tid  = threadIdx.x;
  const int lane = tid & 63;
  const int wv   = tid >> 6;            // 0..7
  const int b0   = blockIdx.x * 64;

  {
    f16x8 z8 = {0, 0, 0, 0, 0, 0, 0, 0};
    for (int i = tid; i < 64 * HID / 8; i += 512) {
      ((f16x8*)h1s)[i] = z8;
      ((f16x8*)h2s)[i] = z8;
    }
    if (tid < 64) {
#pragma unroll
      for (int k = 0; k < 16; ++k) xs16[tid * 16 + k] = (f16)((k == 3) ? 1.f : 0.f);
    }
    if (tid < HID) {
      const int pos = ((tid & 7) << 6) + (tid >> 3);
      fcwT[pos]        = fc_w[tid];
      fcwT[512 + pos]  = fc_w[512 + tid];
      fcwT[1024 + pos] = fc_w[1024 + tid];
      bsh[tid]         = Bb[1536 + tid];          // b1nh
      bsh[512 + tid]   = Bb[2048 + tid];          // b2r
      bsh[1024 + tid]  = Bb[2048 + 512 + tid];    // b2z
      bsh[1536 + tid]  = Bb[2048 + 1024 + tid];   // b2ni
      bsh[2048 + tid]  = Bb[2048 + 1536 + tid];   // b2nh
    }
  }
  __syncthreads();
  if (tid < 64 * 3) {
    const int rr = tid / 3, oo = tid - rr * 3;
    float v = z[(size_t)(b0 + rr) * 6 + 3 + oo];
    xsf[rr * 4 + oo] = v;
    xs16[rr * 16 + oo] = (f16)v;
    out[(size_t)(b0 + rr) * 300 + oo] = v;     // t = 0 output
  }
  __syncthreads();

  const int colid = lane & 31;
  const int khalf = lane >> 5;
  const int klo   = khalf << 4;
  const int patA  = (colid & 7) << 4;
  const int rbase = colid * 1024;
  const int jw    = wv << 6;            // wave owns cols [jw, jw+64)
  const int ct0   = wv << 1;
  const int ct1   = ct0 + 1;

  // bf8 region bases (bytes): per matrix 512KB, per gate 256KB, per ct 16KB
  const unsigned char* W8_1r = W8 + (size_t)ct0 * 16384 + lane * 8;                 // Whh1 r
  const unsigned char* W8_1z = W8 + 262144 + (size_t)ct0 * 16384 + lane * 8;        // Whh1 z
  const unsigned char* W8_ir = W8 + 524288 + (size_t)ct0 * 16384 + lane * 8;        // Wi2 r
  const unsigned char* W8_iz = W8 + 524288 + 262144 + (size_t)ct0 * 16384 + lane * 8;
  const unsigned char* W8_hr = W8 + 1048576 + (size_t)ct0 * 16384 + lane * 8;       // Wh2 r
  const unsigned char* W8_hz = W8 + 1048576 + 262144 + (size_t)ct0 * 16384 + lane * 8;
  // f16 n-gate bases: per matrix 262144 halfs, per ct 16384 halfs
  const f16* Wn_1 = Wn + (size_t)ct0 * 16384 + lane * 8;             // Whh1 n
  const f16* Wn_i = Wn + 262144 + (size_t)ct0 * 16384 + lane * 8;    // Wi2 n
  const f16* Wn_h = Wn + 524288 + (size_t)ct0 * 16384 + lane * 8;    // Wh2 n

  const float fb0 = fc_b[0], fb1 = fc_b[1], fb2 = fc_b[2];
  const int xoff0 = colid * 32 + klo;
  const int xoff1 = (32 + colid) * 32 + klo;

  for (int t = 1; t < NSTEP; ++t) {
    f32x16 aR[2][2], aH[2][2], aZ[2][2];   // acc-class parks only

    // ========== L1 pass r: aR = Whh1_r·h1 + Wx_r·[x|1] (bias in slot) ==========
    {
      f16x8 ax0 = *(const f16x8*)((const char*)xs16 + xoff0);
      f16x8 ax1 = *(const f16x8*)((const char*)xs16 + xoff1);
      f32x16 zz = zero16();
#pragma unroll
      for (int c = 0; c < 2; ++c) {
        f16x8 bx = *(const f16x8*)(Wx + (size_t)(ct0 + c) * 512 + lane * 8);
        aR[c][0] = mfma16(ax0, bx, zz);
        aR[c][1] = mfma16(ax1, bx, zz);
      }
#pragma unroll 2
      for (int kt = 0; kt < 32; ++kt) {
        const int koff = ((kt << 5) | klo) ^ patA;
        f16x8 a0 = *(const f16x8*)((const char*)h1s + rbase + koff);
        f16x8 a1 = *(const f16x8*)((const char*)h1s + 32768 + rbase + koff);
        f16x8 b0 = dec8(*(const u32x2v*)(W8_1r + kt * 512));
        f16x8 b1 = dec8(*(const u32x2v*)(W8_1r + 16384 + kt * 512));
        aR[0][0] = mfma16(a0, b0, aR[0][0]);  aR[0][1] = mfma16(a1, b0, aR[0][1]);
        aR[1][0] = mfma16(a0, b1, aR[1][0]);  aR[1][1] = mfma16(a1, b1, aR[1][1]);
      }
    }
    // ========== L1 pass nH: aH = Whh1_n·h1 (f16 weights) ==========
    {
      f32x16 zz = zero16();
      aH[0][0] = zz; aH[0][1] = zz; aH[1][0] = zz; aH[1][1] = zz;
#pragma unroll 2
      for (int kt = 0; kt < 32; ++kt) {
        const int koff = ((kt << 5) | klo) ^ patA;
        f16x8 a0 = *(const f16x8*)((const char*)h1s + rbase + koff);
        f16x8 a1 = *(const f16x8*)((const char*)h1s + 32768 + rbase + koff);
        f16x8 b0 = *(const f16x8*)(Wn_1 + kt * 512);
        f16x8 b1 = *(const f16x8*)(Wn_1 + 16384 + kt * 512);
        aH[0][0] = mfma16(a0, b0, aH[0][0]);  aH[0][1] = mfma16(a1, b0, aH[0][1]);
        aH[1][0] = mfma16(a0, b1, aH[1][0]);  aH[1][1] = mfma16(a1, b1, aH[1][1]);
      }
    }
    // ---- combine (frees aR): aH <- sigma(aR) * (aH + b1nh); K-ext adds gi_n + b1ni ----
    {
#pragma unroll
      for (int c = 0; c < 2; ++c) {
        const float bnh = bsh[jw + (c << 5) + colid];
#pragma unroll
        for (int tl = 0; tl < 2; ++tl)
#pragma unroll
          for (int q = 0; q < 16; ++q)
            aH[c][tl][q] = sigmoid_f(aR[c][tl][q]) * (aH[c][tl][q] + bnh);
      }
      f16x8 ax0 = *(const f16x8*)((const char*)xs16 + xoff0);
      f16x8 ax1 = *(const f16x8*)((const char*)xs16 + xoff1);
#pragma unroll
      for (int c = 0; c < 2; ++c) {
        f16x8 bx = *(const f16x8*)(Wx + (size_t)(32 + ct0 + c) * 512 + lane * 8);
        aH[c][0] = mfma16(ax0, bx, aH[c][0]);
        aH[c][1] = mfma16(ax1, bx, aH[c][1]);
      }
    }
    // ========== L1 pass z: aZ = Whh1_z·h1 + Wx_z·[x|1] ==========
    {
      f16x8 ax0 = *(const f16x8*)((const char*)xs16 + xoff0);
      f16x8 ax1 = *(const f16x8*)((const char*)xs16 + xoff1);
      f32x16 zz = zero16();
#pragma unroll
      for (int c = 0; c < 2; ++c) {
        f16x8 bx = *(const f16x8*)(Wx + (size_t)(16 + ct0 + c) * 512 + lane * 8);
        aZ[c][0] = mfma16(ax0, bx, zz);
        aZ[c][1] = mfma16(ax1, bx, zz);
      }
#pragma unroll 2
      for (int kt = 0; kt < 32; ++kt) {
        const int koff = ((kt << 5) | klo) ^ patA;
        f16x8 a0 = *(const f16x8*)((const char*)h1s + rbase + koff);
        f16x8 a1 = *(const f16x8*)((const char*)h1s + 32768 + rbase + koff);
        f16x8 b0 = dec8(*(const u32x2v*)(W8_1z + kt * 512));
        f16x8 b1 = dec8(*(const u32x2v*)(W8_1z + 16384 + kt * 512));
        aZ[0][0] = mfma16(a0, b0, aZ[0][0]);  aZ[0][1] = mfma16(a1, b0, aZ[0][1]);
        aZ[1][0] = mfma16(a0, b1, aZ[1][0]);  aZ[1][1] = mfma16(a1, b1, aZ[1][1]);
      }
    }
    __syncthreads();   // all h1_old reads done
    // ---- epi1 (in place) ----
#pragma unroll
    for (int c = 0; c < 2; ++c) {
      const int jxc = 2 * (jw + (c << 5) + colid);
#pragma unroll
      for (int tl = 0; tl < 2; ++tl)
#pragma unroll
        for (int q = 0; q < 16; ++q) {
          const int row = (q & 3) + ((q >> 2) << 3) + (khalf << 2);
          f16* hp = (f16*)((char*)h1s + tl * 32768 + row * 1024 + (jxc ^ ((row & 7) << 4)));
          float zt = sigmoid_f(aZ[c][tl][q]);
          float n  = tanh_f(aH[c][tl][q]);
          float hold = (float)*hp;
          *hp = (f16)((1.0f - zt) * n + zt * hold);
        }
    }
    __syncthreads();   // h1_new visible

    // ========== L2 pass r: aR = Wi2_r·h1 + Wh2_r·h2 (bf8 weights) ==========
    {
      f32x16 zz = zero16();
      aR[0][0] = zz; aR[0][1] = zz; aR[1][0] = zz; aR[1][1] = zz;
#pragma unroll 2
      for (int kt = 0; kt < 32; ++kt) {
        const int koff = ((kt << 5) | klo) ^ patA;
        f16x8 x0 = *(const f16x8*)((const char*)h1s + rbase + koff);
        f16x8 x1 = *(const f16x8*)((const char*)h1s + 32768 + rbase + koff);
        f16x8 y0 = *(const f16x8*)((const char*)h2s + rbase + koff);
        f16x8 y1 = *(const f16x8*)((const char*)h2s + 32768 + rbase + koff);
        f16x8 bi0 = dec8(*(const u32x2v*)(W8_ir + kt * 512));
        f16x8 bi1 = dec8(*(const u32x2v*)(W8_ir + 16384 + kt * 512));
        f16x8 bh0 = dec8(*(const u32x2v*)(W8_hr + kt * 512));
        f16x8 bh1 = dec8(*(const u32x2v*)(W8_hr + 16384 + kt * 512));
        aR[0][0] = mfma16(x0, bi0, aR[0][0]);  aR[0][0] = mfma16(y0, bh0, aR[0][0]);
        aR[0][1] = mfma16(x1, bi0, aR[0][1]);  aR[0][1] = mfma16(y1, bh0, aR[0][1]);
        aR[1][0] = mfma16(x0, bi1, aR[1][0]);  aR[1][0] = mfma16(y0, bh1, aR[1][0]);
        aR[1][1] = mfma16(x1, bi1, aR[1][1]);  aR[1][1] = mfma16(y1, bh1, aR[1][1]);
      }
    }
    // ========== L2 pass nH: aH = Wh2_n·h2 (f16 weights) ==========
    {
      f32x16 zz = zero16();
      aH[0][0] = zz; aH[0][1] = zz; aH[1][0] = zz; aH[1][1] = zz;
#pragma unroll 2
      for (int kt = 0; kt < 32; ++kt) {
        const int koff = ((kt << 5) | klo) ^ patA;
        f16x8 y0 = *(const f16x8*)((const char*)h2s + rbase + koff);
        f16x8 y1 = *(const f16x8*)((const char*)h2s + 32768 + rbase + koff);
        f16x8 b0 = *(const f16x8*)(Wn_h + kt * 512);
        f16x8 b1 = *(const f16x8*)(Wn_h + 16384 + kt * 512);
        aH[0][0] = mfma16(y0, b0, aH[0][0]);  aH[0][1] = mfma16(y1, b0, aH[0][1]);
        aH[1][0] = mfma16(y0, b1, aH[1][0]);  aH[1][1] = mfma16(y1, b1, aH[1][1]);
      }
    }
    // ---- combine (frees aR): aH <- sigma(aR + b2r) * (aH + b2nh) ----
#pragma unroll
    for (int c = 0; c < 2; ++c) {
      const int j = jw + (c << 5) + colid;
      const float br  = bsh[512 + j];
      const float bnh = bsh[2048 + j];
#pragma unroll
      for (int tl = 0; tl < 2; ++tl)
#pragma unroll
        for (int q = 0; q < 16; ++q)
          aH[c][tl][q] = sigmoid_f(aR[c][tl][q] + br) * (aH[c][tl][q] + bnh);
    }
    // ========== L2 pass z: aZ = Wi2_z·h1 + Wh2_z·h2 (bf8 weights) ==========
    {
      f32x16 zz = zero16();
      aZ[0][0] = zz; aZ[0][1] = zz; aZ[1][0] = zz; aZ[1][1] = zz;
#pragma unroll 2
      for (int kt = 0; kt < 32; ++kt) {
        const int koff = ((kt << 5) | klo) ^ patA;
        f16x8 x0 = *(const f16x8*)((const char*)h1s + rbase + koff);
        f16x8 x1 = *(const f16x8*)((const char*)h1s + 32768 + rbase + koff);
        f16x8 y0 = *(const f16x8*)((const char*)h2s + rbase + koff);
        f16x8 y1 = *(const f16x8*)((const char*)h2s + 32768 + rbase + koff);
        f16x8 bi0 = dec8(*(const u32x2v*)(W8_iz + kt * 512));
        f16x8 bi1 = dec8(*(const u32x2v*)(W8_iz + 16384 + kt * 512));
        f16x8 bh0 = dec8(*(const u32x2v*)(W8_hz + kt * 512));
        f16x8 bh1 = dec8(*(const u32x2v*)(W8_hz + 16384 + kt * 512));
        aZ[0][0] = mfma16(x0, bi0, aZ[0][0]);  aZ[0][0] = mfma16(y0, bh0, aZ[0][0]);
        aZ[0][1] = mfma16(x1, bi0, aZ[0][1]);  aZ[0][1] = mfma16(y1, bh0, aZ[0][1]);
        aZ[1][0] = mfma16(x0, bi1, aZ[1][0]);  aZ[1][0] = mfma16(y0, bh1, aZ[1][0]);
        aZ[1][1] = mfma16(x1, bi1, aZ[1][1]);  aZ[1][1] = mfma16(y1, bh1, aZ[1][1]);
      }
    }
    // ========== L2 pass nI: aH += Wi2_n·h1 (f16 weights, C-operand chaining) ==========
    {
#pragma unroll 2
      for (int kt = 0; kt < 32; ++kt) {
        const int koff = ((kt << 5) | klo) ^ patA;
        f16x8 x0 = *(const f16x8*)((const char*)h1s + rbase + koff);
        f16x8 x1 = *(const f16x8*)((const char*)h1s + 32768 + rbase + koff);
        f16x8 b0 = *(const f16x8*)(Wn_i + kt * 512);
        f16x8 b1 = *(const f16x8*)(Wn_i + 16384 + kt * 512);
        aH[0][0] = mfma16(x0, b0, aH[0][0]);  aH[0][1] = mfma16(x1, b0, aH[0][1]);
        aH[1][0] = mfma16(x0, b1, aH[1][0]);  aH[1][1] = mfma16(x1, b1, aH[1][1]);
      }
    }
    __syncthreads();   // all h2_old reads done
    // ---- epi2 (in place) ----
#pragma unroll
    for (int c = 0; c < 2; ++c) {
      const int j = jw + (c << 5) + colid;
      const float bz  = bsh[1024 + j];
      const float bni = bsh[1536 + j];
      const int jxc = 2 * j;
#pragma unroll
      for (int tl = 0; tl < 2; ++tl)
#pragma unroll
        for (int q = 0; q < 16; ++q) {
          const int row = (q & 3) + ((q >> 2) << 3) + (khalf << 2);
          f16* hp = (f16*)((char*)h2s + tl * 32768 + row * 1024 + (jxc ^ ((row & 7) << 4)));
          float zt = sigmoid_f(aZ[c][tl][q] + bz);
          float n  = tanh_f(aH[c][tl][q] + bni);
          float hold = (float)*hp;
          *hp = (f16)((1.0f - zt) * n + zt * hold);
        }
    }
    __syncthreads();   // h2_new visible

    // ================= FC head: 8 waves x 8 rows, 8-lane shuffle reduce =================
    {
      const int rowg = (wv << 3) + (lane >> 3);   // global row 0..63
      const int tl   = rowg >> 5;
      const int rit  = rowg & 31;
      const int sl   = lane & 7;                  // k-slice of 64
      const char* hb = (const char*)h2s + tl * 32768 + rit * 1024;
      const int pat = (rit & 7) << 4;
      float p0 = 0.f, p1 = 0.f, p2 = 0.f;
#pragma unroll
      for (int j = 0; j < 8; ++j) {
        f16x8 hh = *(const f16x8*)(hb + (((sl << 7) | (j << 4)) ^ pat));
#pragma unroll
        for (int i = 0; i < 8; ++i) {
          const float hf = (float)hh[i];
          const int pos = (i << 6) + (sl << 3) + j;
          p0 = fmaf(hf, fcwT[pos], p0);
          p1 = fmaf(hf, fcwT[512 + pos], p1);
          p2 = fmaf(hf, fcwT[1024 + pos], p2);
        }
      }
#pragma unroll
      for (int m = 1; m < 8; m <<= 1) {
        p0 += __shfl_xor(p0, m, 64);
        p1 += __shfl_xor(p1, m, 64);
        p2 += __shfl_xor(p2, m, 64);
      }
      if (sl == 0) {
        float x0 = xsf[(rowg << 2) + 0] + 0.1f * tanh_f(p0 + fb0);
        float x1 = xsf[(rowg << 2) + 1] + 0.1f * tanh_f(p1 + fb1);
        float x2 = xsf[(rowg << 2) + 2] + 0.1f * tanh_f(p2 + fb2);
        xsf[(rowg << 2) + 0] = x0;  xs16[rowg * 16 + 0] = (f16)x0;
        xsf[(rowg << 2) + 1] = x1;  xs16[rowg * 16 + 1] = (f16)x1;
        xsf[(rowg << 2) + 2] = x2;  xs16[rowg * 16 + 2] = (f16)x2;
        float* op = out + (size_t)(b0 + rowg) * 300 + (size_t)t * 3;
        op[0] = x0; op[1] = x1; op[2] = x2;
      }
    }
    __syncthreads();
  }
}

extern "C" void kernel_launch(void* const* d_in, const int* in_sizes, int n_in,
                              void* d_out, int out_size, void* d_ws, size_t ws_size,
                              hipStream_t stream) {
  const float* z     = (const float*)d_in[0];
  const float* w_ih1 = (const float*)d_in[1];
  const float* w_hh1 = (const float*)d_in[2];
  const float* b_ih1 = (const float*)d_in[3];
  const float* b_hh1 = (const float*)d_in[4];
  const float* w_ih2 = (const float*)d_in[5];
  const float* w_hh2 = (const float*)d_in[6];
  const float* b_ih2 = (const float*)d_in[7];
  const float* b_hh2 = (const float*)d_in[8];
  const float* fc_w  = (const float*)d_in[9];
  const float* fc_b  = (const float*)d_in[10];
  float* out = (float*)d_out;

  // workspace layout (total ~3.1 MB):
  //   Wn  : f16 n-gate tiles, 3 x 262144 halfs  = 1.5 MB
  //   W8  : bf8 r,z tiles,    3 x 524288 bytes  = 1.5 MB
  //   Wx  : f16 K-ext w_ih1,  48*512 halfs      = 48 KB
  //   Bb  : 4096 floats                          = 16 KB
  f16*           Wn = (f16*)d_ws;
  unsigned char* W8 = (unsigned char*)d_ws + (size_t)3 * 262144 * 2;
  f16*           Wx = (f16*)(W8 + (size_t)3 * 524288);
  float*         Bb = (float*)((char*)Wx + (size_t)48 * 512 * 2);

  const int nbatch = in_sizes[0] / 6;

  pack_wn<<<128, 256, 0, stream>>>(w_hh1, Wn);
  pack_wn<<<128, 256, 0, stream>>>(w_ih2, Wn + 262144);
  pack_wn<<<128, 256, 0, stream>>>(w_hh2, Wn + 2 * 262144);
  pack_w8<<<256, 256, 0, stream>>>(w_hh1, W8);
  pack_w8<<<256, 256, 0, stream>>>(w_ih2, W8 + 524288);
  pack_w8<<<256, 256, 0, stream>>>(w_hh2, W8 + 2 * 524288);
  pack_wx<<<12, 256, 0, stream>>>(w_ih1, b_ih1, b_hh1, Wx);
  pack_bias<<<8, 256, 0, stream>>>(b_ih1, b_hh1, Bb);
  pack_bias<<<8, 256, 0, stream>>>(b_ih2, b_hh2, Bb + 2048);

  gru_fused<<<nbatch / 64, 512, 0, stream>>>(z, fc_w, fc_b, Wn, W8, Wx, Bb, out);
}